// Round 1
// 522.725 us; speedup vs baseline: 1.0483x; 1.0483x over previous
//
#include <hip/hip_runtime.h>
#include <hip/hip_bf16.h>
#include <hip/hip_fp16.h>

// GCN: 2x GCNConv (symmetric norm, self-loops) + linear head.
// N=100000, E=3200000, IN=128, HID=64, LAB=121.
//
// R7: aggregate re-mapped. Old layout = 1 thread per (row, feature): each
// gather instr moved 128 B (2 B/lane ushort) + ~5 VALU/edge addr+cvt ->
// issue/MLP-bound at 3.3 TB/s, VALUBusy 39%. New layout = one wave per dst
// row, lanes = 8 edge-slots x 8 feature-octets, dwordx4 (16 B/lane): one
// load instr = 8 edges = 1 KB; srcs reads coalesce 8-wide; x2 unroll = 2 KB
// in flight/wave. Epilogue: 3x shfl_xor slot-tree, slot-0 float4 stores.
// feat2 aligned up to 16 B (dwordx4 requirement).
// Retained from R4-R6: two-level dst sort with block-private full-line runs;
// fp16 feat2 (halves gather payload + working set); bucket_sort emits
// row_ptr+dinv (no per-node histogram pass); self-loop folded as deg+1 and
// epilogue term; dinv[src] folded into GEMM rowscale; GEMM 4x4 reg tile.

#define IN_DIM 128
#define HID 64
#define N_LAB 121
#define NB_BLK 256        // level-1 blocks (chunks)

// ---- generic 3-kernel exclusive scan (used for the M1 = nbuk*NB_BLK counts) ----
__global__ void scan1(const int* __restrict__ in, int* __restrict__ out,
                      int* __restrict__ bsums, int n) {
    __shared__ int s[256];
    int i = blockIdx.x * 256 + threadIdx.x;
    int v = (i < n) ? in[i] : 0;
    s[threadIdx.x] = v;
    __syncthreads();
    for (int off = 1; off < 256; off <<= 1) {
        int t = (threadIdx.x >= off) ? s[threadIdx.x - off] : 0;
        __syncthreads();
        s[threadIdx.x] += t;
        __syncthreads();
    }
    if (i < n) out[i] = s[threadIdx.x] - v;  // exclusive
    if (threadIdx.x == 255) bsums[blockIdx.x] = s[255];
}

__global__ void scan2(int* __restrict__ bsums, int nb) {  // single block, nb <= 512
    __shared__ int s[512];
    int v = (threadIdx.x < nb) ? bsums[threadIdx.x] : 0;
    s[threadIdx.x] = v;
    __syncthreads();
    for (int off = 1; off < 512; off <<= 1) {
        int t = (threadIdx.x >= off) ? s[threadIdx.x - off] : 0;
        __syncthreads();
        s[threadIdx.x] += t;
        __syncthreads();
    }
    if (threadIdx.x < nb) bsums[threadIdx.x] = s[threadIdx.x] - v;  // exclusive
}

__global__ void scan_add(int* __restrict__ out, const int* __restrict__ bsums, int n) {
    int i = blockIdx.x * 256 + threadIdx.x;
    if (i < n) out[i] += bsums[blockIdx.x];
}

// ---- L1 pass A: per-block per-bucket counts ----
__global__ __launch_bounds__(256) void bucket_count(const int* __restrict__ dst,
                                                    int* __restrict__ counts,
                                                    int nbuk, int chunk, int E) {
    extern __shared__ int c[];
    for (int j = threadIdx.x; j < nbuk; j += 256) c[j] = 0;
    __syncthreads();
    int beg = blockIdx.x * chunk;
    int end = min(beg + chunk, E);
    for (int i = beg + threadIdx.x; i < end; i += 256)
        atomicAdd(&c[dst[i] >> 8], 1);
    __syncthreads();
    for (int j = threadIdx.x; j < nbuk; j += 256)
        counts[j * NB_BLK + blockIdx.x] = c[j];
}

// ---- L1 pass B: scatter into private contiguous runs ----
__global__ __launch_bounds__(256) void bucket_scatter(const int* __restrict__ src,
                                                      const int* __restrict__ dst,
                                                      const int* __restrict__ base,
                                                      int* __restrict__ bucketed,
                                                      int nbuk, int chunk, int E) {
    extern __shared__ int c[];
    for (int j = threadIdx.x; j < nbuk; j += 256) c[j] = 0;
    __syncthreads();
    int beg = blockIdx.x * chunk;
    int end = min(beg + chunk, E);
    for (int i = beg + threadIdx.x; i < end; i += 256) {
        int d = dst[i];
        int b = d >> 8;
        int r = atomicAdd(&c[b], 1);
        int pos = base[b * NB_BLK + blockIdx.x] + r;
        bucketed[pos] = ((d & 255) << 17) | src[i];  // src < 2^17
    }
}

// ---- L2: within-bucket sort into final CSR srcs; emits row_ptr + dinv ----
__global__ __launch_bounds__(256) void bucket_sort(const int* __restrict__ bucketed,
                                                   const int* __restrict__ base,
                                                   int* __restrict__ srcs,
                                                   int* __restrict__ row_ptr,
                                                   float* __restrict__ dinv,
                                                   int nbuk, int N, int E) {
    __shared__ int h[256];
    __shared__ int cur[256];
    int b = blockIdx.x;
    int nodeBase = b << 8;
    int s = base[b * NB_BLK];
    int e = (b == nbuk - 1) ? E : base[(b + 1) * NB_BLK];
    h[threadIdx.x] = 0;
    __syncthreads();
    for (int i = s + threadIdx.x; i < e; i += 256)
        atomicAdd(&h[bucketed[i] >> 17], 1);
    __syncthreads();
    int v = h[threadIdx.x];
    for (int off = 1; off < 256; off <<= 1) {  // inclusive Hillis-Steele
        int t = (threadIdx.x >= off) ? h[threadIdx.x - off] : 0;
        __syncthreads();
        h[threadIdx.x] += t;
        __syncthreads();
    }
    int excl = h[threadIdx.x] - v;
    cur[threadIdx.x] = excl;
    int node = nodeBase + threadIdx.x;
    if (node < N) {
        row_ptr[node] = s + excl;
        dinv[node] = rsqrtf((float)v + 1.0f);  // +1 = self loop
    }
    if (b == nbuk - 1 && threadIdx.x == 0) row_ptr[N] = E;
    __syncthreads();
    for (int i = s + threadIdx.x; i < e; i += 256) {
        int p = bucketed[i];
        int d = p >> 17;
        int r = atomicAdd(&cur[d], 1);
        srcs[s + r] = p & 0x1FFFF;
    }
}

// ---- C[M,N] = (A[M,K] @ B[K,N]) * rowscale[r] + bias. LDS-staged, 2D reg tile ----
// 64-row tile. Thread (cg, rg) owns cols 4cg..4cg+3 and rows rg + RG*j.
// Per k-quad: 4 b128 A reads (broadcast across cg) + 4 b128 B reads -> 64 fmaf.
template <int K, int N, typename OT>
__global__ __launch_bounds__(256) void gemm_kernel(
        const float* __restrict__ A, const float* __restrict__ B,
        const float* __restrict__ bias, const float* __restrict__ rowscale,
        OT* __restrict__ C, int M) {
    constexpr int ROWS = 64;
    constexpr int NPAD = (N <= 64) ? 64 : 128;
    constexpr int CG = NPAD / 4;     // column groups (16 or 32)
    constexpr int RG = 256 / CG;     // thread rows (16 or 8)
    constexpr int RPT = ROWS / RG;   // rows per thread (4 or 8)
    __shared__ float Bs[K * NPAD];
    __shared__ float As[ROWS * K];

    // stage B (zero-pad cols N..NPAD)
    for (int i = threadIdx.x; i < K * NPAD; i += 256) {
        int c = i & (NPAD - 1);
        int k = i / NPAD;
        Bs[i] = (c < N) ? B[k * N + c] : 0.f;
    }
    // stage A tile (coalesced float4); tail block loads only valid rows
    const int row_base = blockIdx.x * ROWS;
    const float* Ablk = A + (size_t)row_base * K;
    int avail = (M - row_base) * K;
    if (avail > ROWS * K) avail = ROWS * K;
    const int nvec = avail >> 2;  // K % 4 == 0
    const float4* __restrict__ Av = (const float4*)Ablk;
    float4* Asv = (float4*)As;
    for (int i = threadIdx.x; i < nvec; i += 256) Asv[i] = Av[i];
    __syncthreads();

    const int cg = threadIdx.x % CG;
    const int rg = threadIdx.x / CG;

    float acc[RPT][4];
    #pragma unroll
    for (int j = 0; j < RPT; ++j) {
        acc[j][0] = 0.f; acc[j][1] = 0.f; acc[j][2] = 0.f; acc[j][3] = 0.f;
    }

    for (int k = 0; k < K; k += 4) {
        float4 Bq[4];
        #pragma unroll
        for (int kk = 0; kk < 4; ++kk)
            Bq[kk] = *(const float4*)&Bs[(k + kk) * NPAD + cg * 4];
        #pragma unroll
        for (int j = 0; j < RPT; ++j) {
            const float4 Aq = *(const float4*)&As[(rg + RG * j) * K + k];
            #pragma unroll
            for (int c = 0; c < 4; ++c) {
                const float b0 = ((const float*)&Bq[0])[c];
                const float b1 = ((const float*)&Bq[1])[c];
                const float b2 = ((const float*)&Bq[2])[c];
                const float b3 = ((const float*)&Bq[3])[c];
                float a = acc[j][c];
                a = fmaf(Aq.x, b0, a);
                a = fmaf(Aq.y, b1, a);
                a = fmaf(Aq.z, b2, a);
                a = fmaf(Aq.w, b3, a);
                acc[j][c] = a;
            }
        }
    }

    // bias for this thread's 4 cols (guarded for N=121 tail)
    float bv[4];
    #pragma unroll
    for (int c = 0; c < 4; ++c) {
        int col = cg * 4 + c;
        bv[c] = (bias && col < N) ? bias[col] : 0.f;
    }

    #pragma unroll
    for (int j = 0; j < RPT; ++j) {
        const int r = row_base + rg + RG * j;
        if (r >= M) continue;
        const float sc = rowscale ? rowscale[r] : 1.0f;
        float o[4];
        #pragma unroll
        for (int c = 0; c < 4; ++c) o[c] = fmaf(acc[j][c], sc, bv[c]);
        OT* Crow = C + (size_t)r * N;
        if constexpr (sizeof(OT) == 4 && (N % 4 == 0)) {
            *(float4*)&Crow[cg * 4] = make_float4(o[0], o[1], o[2], o[3]);
        } else if constexpr (sizeof(OT) == 2 && (N % 4 == 0)) {
            __half2* p = (__half2*)&Crow[cg * 4];
            p[0] = __floats2half2_rn(o[0], o[1]);
            p[1] = __floats2half2_rn(o[2], o[3]);
        } else {
            #pragma unroll
            for (int c = 0; c < 4; ++c) {
                int col = cg * 4 + c;
                if (col < N) Crow[col] = (OT)o[c];
            }
        }
    }
}

// ---- pull aggregation: one wave per dst row ----
// Lanes = 8 edge-slots x 8 feature-octets. Each lane gathers dwordx4 (8 fp16
// features, 16 B) for its slot's edge: one load instr = 8 edges = 1 KB.
// x2 unroll = 2 KB in flight per wave. fp32 accum; 3-round shfl_xor tree over
// slots; slot-0 lanes store 2x float4 (contiguous 256 B per row).
// out[r] = relu(dinv[r] * (feat2[r] + sum_{s in N_in(r)} feat2[s]) + bias)
__global__ __launch_bounds__(256) void aggregate(
        const __half* __restrict__ feat2, const int* __restrict__ rp,
        const int* __restrict__ srcs, const float* __restrict__ dinv,
        const float* __restrict__ bias, float* __restrict__ out, int N) {
    const int wid = (int)((((size_t)blockIdx.x * 256) + threadIdx.x) >> 6);
    if (wid >= N) return;  // wave-uniform
    const int lane = threadIdx.x & 63;
    const int slot = lane >> 3;          // 0..7 edge slot
    const int oct  = lane & 7;           // feature octet: feats oct*8 .. oct*8+7
    const size_t fbase = (size_t)oct << 3;

    float acc[8];
    #pragma unroll
    for (int i = 0; i < 8; ++i) acc[i] = 0.f;

    // self-loop term: slot 0 loads own row's octet (counted once after tree)
    if (slot == 0) {
        const uint4 raw = *(const uint4*)(feat2 + (((size_t)wid << 6) + fbase));
        const __half2* h = (const __half2*)&raw;
        #pragma unroll
        for (int i = 0; i < 4; ++i) {
            const float2 f = __half22float2(h[i]);
            acc[2 * i]     += f.x;
            acc[2 * i + 1] += f.y;
        }
    }

    const int beg = rp[wid], end = rp[wid + 1];
    int e = beg;
    for (; e + 16 <= end; e += 16) {  // 2 independent 8-edge gathers in flight
        const int s0 = srcs[e + slot];
        const int s1 = srcs[e + 8 + slot];
        const uint4 r0 = *(const uint4*)(feat2 + (((size_t)s0 << 6) + fbase));
        const uint4 r1 = *(const uint4*)(feat2 + (((size_t)s1 << 6) + fbase));
        const __half2* h0 = (const __half2*)&r0;
        const __half2* h1 = (const __half2*)&r1;
        #pragma unroll
        for (int i = 0; i < 4; ++i) {
            const float2 f0 = __half22float2(h0[i]);
            const float2 f1 = __half22float2(h1[i]);
            acc[2 * i]     += f0.x + f1.x;
            acc[2 * i + 1] += f0.y + f1.y;
        }
    }
    for (; e < end; e += 8) {  // guarded 8-edge tail
        const int idx = e + slot;
        if (idx < end) {
            const int s = srcs[idx];
            const uint4 r0 = *(const uint4*)(feat2 + (((size_t)s << 6) + fbase));
            const __half2* h0 = (const __half2*)&r0;
            #pragma unroll
            for (int i = 0; i < 4; ++i) {
                const float2 f = __half22float2(h0[i]);
                acc[2 * i]     += f.x;
                acc[2 * i + 1] += f.y;
            }
        }
    }

    // reduce across the 8 slots (lane bits 3..5)
    #pragma unroll
    for (int m = 8; m <= 32; m <<= 1) {
        #pragma unroll
        for (int i = 0; i < 8; ++i)
            acc[i] += __shfl_xor(acc[i], m, 64);
    }

    if (slot == 0) {
        const float sc = dinv[wid];
        float o[8];
        #pragma unroll
        for (int i = 0; i < 8; ++i)
            o[i] = fmaxf(fmaf(acc[i], sc, bias[fbase + i]), 0.f);
        float4* dst4 = (float4*)(out + (((size_t)wid << 6) + fbase));
        dst4[0] = make_float4(o[0], o[1], o[2], o[3]);
        dst4[1] = make_float4(o[4], o[5], o[6], o[7]);
    }
}

extern "C" void kernel_launch(void* const* d_in, const int* in_sizes, int n_in,
                              void* d_out, int out_size, void* d_ws, size_t ws_size,
                              hipStream_t stream) {
    const float* x    = (const float*)d_in[0];
    const int*   ei   = (const int*)d_in[1];
    const float* W1   = (const float*)d_in[2];
    const float* b1   = (const float*)d_in[3];
    const float* W2   = (const float*)d_in[4];
    const float* b2   = (const float*)d_in[5];
    const float* Wout = (const float*)d_in[6];
    const float* bout = (const float*)d_in[7];
    float* out = (float*)d_out;

    const int N = in_sizes[0] / IN_DIM;   // 100000
    const int E = in_sizes[1] / 2;        // 3200000
    const int* srcI = ei;
    const int* dstI = ei + E;

    const int nbuk = (N + 255) >> 8;      // 391 coarse buckets
    const int M1 = nbuk * NB_BLK;         // 100096 count entries
    const int chunk = (E + NB_BLK - 1) / NB_BLK;

    // workspace carve-up
    int*    row_ptr = (int*)d_ws;                   // [N+1]
    float*  dinv    = (float*)(row_ptr + (N + 1));  // [N]
    int*    counts  = (int*)(dinv + N);             // [M1]
    int*    base    = counts + M1;                  // [M1]
    int*    bsums2  = base + M1;                    // [512]
    int*    srcs    = bsums2 + 512;                 // [E]
    // feat2 must be 16-B aligned (dwordx4 gathers in aggregate)
    __half* feat2   = (__half*)(((uintptr_t)(srcs + E) + 15) & ~(uintptr_t)15);
    float*  hbuf    = (float*)(feat2 + (size_t)N * HID);  // [N, HID] fp32
    int*    bucketed = (int*)feat2;                 // [E] ints, aliases feat2 (dead until GEMM1)

    const int nbM = (M1 + 255) / 256;               // 391
    const int gemmBlocks = (N + 63) / 64;
    const int aggBlocks = (int)(((size_t)N * HID + 255) / 256);
    const size_t ldsBuk = (size_t)nbuk * sizeof(int);

    // ---- two-level sort: edges grouped by dst into srcs; emits row_ptr+dinv ----
    bucket_count<<<NB_BLK, 256, ldsBuk, stream>>>(dstI, counts, nbuk, chunk, E);
    scan1<<<nbM, 256, 0, stream>>>(counts, base, bsums2, M1);
    scan2<<<1, 512, 0, stream>>>(bsums2, nbM);
    scan_add<<<nbM, 256, 0, stream>>>(base, bsums2, M1);
    bucket_scatter<<<NB_BLK, 256, ldsBuk, stream>>>(srcI, dstI, base, bucketed, nbuk, chunk, E);
    bucket_sort<<<nbuk, 256, 0, stream>>>(bucketed, base, srcs, row_ptr, dinv, nbuk, N, E);

    // ---- layer 1 ----
    gemm_kernel<IN_DIM, HID, __half><<<gemmBlocks, 256, 0, stream>>>(x, W1, nullptr, dinv, feat2, N);
    aggregate<<<aggBlocks, 256, 0, stream>>>(feat2, row_ptr, srcs, dinv, b1, hbuf, N);

    // ---- layer 2 ----
    gemm_kernel<HID, HID, __half><<<gemmBlocks, 256, 0, stream>>>(hbuf, W2, nullptr, dinv, feat2, N);
    aggregate<<<aggBlocks, 256, 0, stream>>>(feat2, row_ptr, srcs, dinv, b2, hbuf, N);

    // ---- head ----
    gemm_kernel<HID, N_LAB, float><<<gemmBlocks, 256, 0, stream>>>(hbuf, Wout, bout, nullptr, out, N);
}